// Round 8
// baseline (647.048 us; speedup 1.0000x reference)
//
#include <hip/hip_runtime.h>
#include <hip/hip_cooperative_groups.h>
#include <math.h>

namespace cg = cooperative_groups;

#define HS 4096
#define NIN 17
#define NBLK 512                    // 2 blocks/CU — 2x co-residency margin
#define CHUNKS 128                  // phase-A row chunks
#define ROWS 32                     // rows per chunk (CHUNKS*ROWS = HS)
#define PER_BLK (HS * HS / NBLK)    // 32768 elements per block (copies/update)

typedef float vfloat4 __attribute__((ext_vector_type(4)));

// ---------------- shared phase bodies (device functions) ----------------

__device__ __forceinline__ void phaseA_body(
    int b, int tid, const float* __restrict__ hidden,
    const float* __restrict__ w, const float* __restrict__ alpha,
    const float* __restrict__ hebb, const float* __restrict__ et,
    const float* __restrict__ pw, float* __restrict__ partial,
    float* __restrict__ out_et, float* __restrict__ out_pw) {
  const int colg = b & 3;           // 4 col groups x 256 lanes x float4 = 4096
  const int chunk = b >> 2;         // 0..127
  const int j4 = colg * 256 + tid;
  const int row0 = chunk * ROWS;
  const size_t base = (size_t)row0 * (HS / 4) + j4;
  const vfloat4* wp = reinterpret_cast<const vfloat4*>(w) + base;
  const vfloat4* ap = reinterpret_cast<const vfloat4*>(alpha) + base;
  const vfloat4* bp = reinterpret_cast<const vfloat4*>(hebb) + base;
  vfloat4 acc = (vfloat4)(0.f);
#pragma unroll 8
  for (int r = 0; r < ROWS; ++r) {
    const float h = hidden[row0 + r];                 // wave-uniform
    const vfloat4 wv = wp[(size_t)r * (HS / 4)];
    const vfloat4 av = ap[(size_t)r * (HS / 4)];
    const vfloat4 bv = bp[(size_t)r * (HS / 4)];
#pragma unroll
    for (int c = 0; c < 4; ++c)
      acc[c] = fmaf(h, fmaf(av[c], bv[c], wv[c]), acc[c]);
  }
  reinterpret_cast<vfloat4*>(partial)[(size_t)chunk * (HS / 4) + j4] = acc;

  // et/pw pass-through interleaved with the read burst (fills write channel).
  const size_t cb = (size_t)b * PER_BLK + tid;
#pragma unroll 8
  for (int i = 0; i < PER_BLK / 256; ++i) {
    const size_t t = cb + (size_t)i * 256;
    out_et[t] = et[t];
    out_pw[t] = pw[t];
  }
}

__device__ __forceinline__ void phaseB_body(
    int b, int tid, const float* __restrict__ partial,
    const float* __restrict__ inputs, const float* __restrict__ i2h_w,
    const float* __restrict__ i2h_b, float* __restrict__ out_hactiv) {
  const int g = tid >> 6, lane = tid & 63;   // 4 waves/block
#pragma unroll
  for (int c = 0; c < 2; ++c) {              // 2048 waves x 2 cols = 4096
    const int j = (b * 4 + g) + 2048 * c;
    float s = 0.f;
#pragma unroll
    for (int i = 0; i < CHUNKS / 64; ++i)
      s += partial[(size_t)(lane + 64 * i) * HS + j];
    if (lane < NIN) s = fmaf(inputs[lane], i2h_w[j * NIN + lane], s);
#pragma unroll
    for (int off = 32; off > 0; off >>= 1) s += __shfl_down(s, off, 64);
    if (lane == 0) out_hactiv[j] = tanhf(s + i2h_b[j]);
  }
}

__device__ __forceinline__ void phaseC_body(
    int b, int tid, const float* __restrict__ hidden,
    const float* __restrict__ hebb, const float* __restrict__ eta,
    const float* __restrict__ h2o_w, const float* __restrict__ h2o_b,
    const float* __restrict__ h2v_w, const float* __restrict__ h2v_b,
    const float* __restrict__ hactiv, float* __restrict__ out_heads,
    float* __restrict__ out_hebb) {
  if (b < 5 && tid < 64) {
    const float* wrow = (b < 4) ? (h2o_w + (size_t)b * HS) : h2v_w;
    float s = 0.f;
    for (int i = tid; i < HS; i += 64) s = fmaf(hactiv[i], wrow[i], s);
#pragma unroll
    for (int off = 32; off > 0; off >>= 1) s += __shfl_down(s, off, 64);
    if (tid == 0) out_heads[b] = s + ((b < 4) ? h2o_b[b] : h2v_b[0]);
  }
  const float e = eta[0];
  const float ome = 1.f - e;
  const size_t cb = (size_t)b * PER_BLK + tid;
#pragma unroll 8
  for (int i = 0; i < PER_BLK / 256; ++i) {
    const size_t t = cb + (size_t)i * 256;
    const float hi = hidden[t >> 12];
    const float ha = hactiv[t & (HS - 1)];
    out_hebb[t] = fmaf(ome, hebb[t], e * hi * ha);
  }
}

// ---------------- cooperative fused kernel ----------------

__global__ __launch_bounds__(256, 2) void fused_k(
    const float* __restrict__ inputs, const float* __restrict__ hidden,
    const float* __restrict__ hebb, const float* __restrict__ et,
    const float* __restrict__ pw, const float* __restrict__ i2h_w,
    const float* __restrict__ i2h_b, const float* __restrict__ w,
    const float* __restrict__ alpha, const float* __restrict__ eta,
    const float* __restrict__ h2o_w, const float* __restrict__ h2o_b,
    const float* __restrict__ h2v_w, const float* __restrict__ h2v_b,
    float* __restrict__ partial, float* __restrict__ out_heads,
    float* __restrict__ out_hactiv, float* __restrict__ out_hebb,
    float* __restrict__ out_et, float* __restrict__ out_pw) {
  cg::grid_group grid = cg::this_grid();
  phaseA_body(blockIdx.x, threadIdx.x, hidden, w, alpha, hebb, et, pw,
              partial, out_et, out_pw);
  grid.sync();
  phaseB_body(blockIdx.x, threadIdx.x, partial, inputs, i2h_w, i2h_b,
              out_hactiv);
  grid.sync();
  phaseC_body(blockIdx.x, threadIdx.x, hidden, hebb, eta, h2o_w, h2o_b,
              h2v_w, h2v_b, out_hactiv, out_heads, out_hebb);
}

// ---------------- fallback kernels (ordinary launches) ----------------

__global__ __launch_bounds__(256, 2) void phaseA_k(
    const float* __restrict__ hidden, const float* __restrict__ w,
    const float* __restrict__ alpha, const float* __restrict__ hebb,
    const float* __restrict__ et, const float* __restrict__ pw,
    float* __restrict__ partial, float* __restrict__ out_et,
    float* __restrict__ out_pw) {
  phaseA_body(blockIdx.x, threadIdx.x, hidden, w, alpha, hebb, et, pw,
              partial, out_et, out_pw);
}

__global__ __launch_bounds__(256, 2) void phaseB_k(
    const float* __restrict__ partial, const float* __restrict__ inputs,
    const float* __restrict__ i2h_w, const float* __restrict__ i2h_b,
    float* __restrict__ out_hactiv) {
  phaseB_body(blockIdx.x, threadIdx.x, partial, inputs, i2h_w, i2h_b,
              out_hactiv);
}

__global__ __launch_bounds__(256, 2) void phaseC_k(
    const float* __restrict__ hidden, const float* __restrict__ hebb,
    const float* __restrict__ eta, const float* __restrict__ h2o_w,
    const float* __restrict__ h2o_b, const float* __restrict__ h2v_w,
    const float* __restrict__ h2v_b, const float* __restrict__ hactiv,
    float* __restrict__ out_heads, float* __restrict__ out_hebb) {
  phaseC_body(blockIdx.x, threadIdx.x, hidden, hebb, eta, h2o_w, h2o_b,
              h2v_w, h2v_b, hactiv, out_heads, out_hebb);
}

extern "C" void kernel_launch(void* const* d_in, const int* in_sizes, int n_in,
                              void* d_out, int out_size, void* d_ws, size_t ws_size,
                              hipStream_t stream) {
  const float* inputs = (const float*)d_in[0];
  const float* hidden = (const float*)d_in[1];
  const float* hebb   = (const float*)d_in[2];
  const float* et     = (const float*)d_in[3];
  const float* pw     = (const float*)d_in[4];
  const float* i2h_w  = (const float*)d_in[5];
  const float* i2h_b  = (const float*)d_in[6];
  const float* w      = (const float*)d_in[7];
  const float* alpha  = (const float*)d_in[8];
  const float* eta    = (const float*)d_in[9];
  const float* h2o_w  = (const float*)d_in[10];
  const float* h2o_b  = (const float*)d_in[11];
  const float* h2v_w  = (const float*)d_in[12];
  const float* h2v_b  = (const float*)d_in[13];

  float* out = (float*)d_out;
  const size_t NSQ = (size_t)HS * HS;
  float* out_heads  = out;               // activout[4] + valueout[1]
  float* out_hactiv = out + 5;           // [HS]
  float* out_hebb   = out + 5 + HS;      // [HS*HS] (float offset 4101)
  float* out_et     = out_hebb + NSQ;
  float* out_pw     = out_et + NSQ;

  // Partial scratch: 128*4096 floats = 2 MB. Prefer d_ws; else an aligned
  // slice of the hebb output region (read in phase B, overwritten in phase C;
  // the grid.sync()/kernel boundary between them guarantees ordering).
  const size_t need = (size_t)CHUNKS * HS * sizeof(float);
  float* partial = (ws_size >= need) ? (float*)d_ws
                                     : (out_hebb + 3 /* float off 4104, 16B-aligned */);

  void* args[] = {
      (void*)&inputs, (void*)&hidden, (void*)&hebb, (void*)&et, (void*)&pw,
      (void*)&i2h_w, (void*)&i2h_b, (void*)&w, (void*)&alpha, (void*)&eta,
      (void*)&h2o_w, (void*)&h2o_b, (void*)&h2v_w, (void*)&h2v_b,
      (void*)&partial, (void*)&out_heads, (void*)&out_hactiv,
      (void*)&out_hebb, (void*)&out_et, (void*)&out_pw};
  hipError_t err = hipLaunchCooperativeKernel(
      (const void*)fused_k, dim3(NBLK), dim3(256), args, 0, stream);
  if (err != hipSuccess) {
    (void)hipGetLastError();  // clear sticky error; use ordinary launches
    hipLaunchKernelGGL(phaseA_k, dim3(NBLK), dim3(256), 0, stream,
                       hidden, w, alpha, hebb, et, pw, partial, out_et, out_pw);
    hipLaunchKernelGGL(phaseB_k, dim3(NBLK), dim3(256), 0, stream,
                       partial, inputs, i2h_w, i2h_b, out_hactiv);
    hipLaunchKernelGGL(phaseC_k, dim3(NBLK), dim3(256), 0, stream,
                       hidden, hebb, eta, h2o_w, h2o_b, h2v_w, h2v_b,
                       out_hactiv, out_heads, out_hebb);
  }
}